// Round 1
// baseline (1925.484 us; speedup 1.0000x reference)
//
#include <hip/hip_runtime.h>
#include <math.h>

// Problem constants (from reference): N=100000, E=1600000, F_IN=8, H=128,
// L=4, E_FEAT=16, G=256, OUT=256. N/E derived from in_sizes at launch.
#define GG 256

// ---------- h = x @ emb_W + emb_b  ([N,8]@[8,128]) ----------
__global__ __launch_bounds__(256) void k_emb(const float* __restrict__ x,
    const float* __restrict__ W, const float* __restrict__ b,
    float* __restrict__ h, int N) {
  int idx = blockIdx.x * 256 + threadIdx.x;      // one float4 of output per thread
  if (idx >= N * 32) return;
  int n = idx >> 5, q = idx & 31;
  const float* xr = x + (size_t)n * 8;
  float xs[8];
#pragma unroll
  for (int k = 0; k < 8; ++k) xs[k] = xr[k];
  float4 acc = ((const float4*)b)[q];
#pragma unroll
  for (int k = 0; k < 8; ++k) {
    float4 w = ((const float4*)(W + (size_t)k * 128))[q];
    acc.x += xs[k] * w.x; acc.y += xs[k] * w.y;
    acc.z += xs[k] * w.z; acc.w += xs[k] * w.w;
  }
  ((float4*)h)[idx] = acc;
}

// ---------- CSR build ----------
__global__ void k_hist(const int* __restrict__ dst, int* __restrict__ deg, int E) {
  int e = blockIdx.x * blockDim.x + threadIdx.x;
  if (e < E) atomicAdd(&deg[dst[e]], 1);
}

__global__ __launch_bounds__(256) void k_scan_reduce(const int* __restrict__ deg,
    int* __restrict__ bsum, int N) {
  __shared__ int sd[256];
  int i = blockIdx.x * 256 + threadIdx.x;
  sd[threadIdx.x] = (i < N) ? deg[i] : 0;
  __syncthreads();
  for (int s = 128; s > 0; s >>= 1) {
    if (threadIdx.x < s) sd[threadIdx.x] += sd[threadIdx.x + s];
    __syncthreads();
  }
  if (threadIdx.x == 0) bsum[blockIdx.x] = sd[0];
}

__global__ void k_scan_mid(int* bsum, int nb) {
  if (threadIdx.x == 0 && blockIdx.x == 0) {
    int run = 0;
    for (int i = 0; i < nb; ++i) { int t = bsum[i]; bsum[i] = run; run += t; }
  }
}

__global__ __launch_bounds__(256) void k_scan_final(const int* __restrict__ deg,
    const int* __restrict__ bsum, int* __restrict__ offs,
    int* __restrict__ cursor, int N) {
  __shared__ int sd[256];
  int t = threadIdx.x;
  int i = blockIdx.x * 256 + t;
  int v = (i < N) ? deg[i] : 0;
  sd[t] = v; __syncthreads();
  for (int d = 1; d < 256; d <<= 1) {           // Hillis-Steele inclusive scan
    int xv = (t >= d) ? sd[t - d] : 0;
    __syncthreads();
    sd[t] += xv;
    __syncthreads();
  }
  int off = bsum[blockIdx.x] + sd[t] - v;       // exclusive
  if (i < N) {
    offs[i] = off; cursor[i] = off;
    if (i == N - 1) offs[N] = off + v;
  }
}

__global__ void k_fill(const int* __restrict__ src, const int* __restrict__ dst,
    const float* __restrict__ attr, int* __restrict__ cursor,
    int* __restrict__ csrc, float* __restrict__ cattr, int E) {
  int e = blockIdx.x * blockDim.x + threadIdx.x;
  if (e >= E) return;
  int d = dst[e];
  int pos = atomicAdd(&cursor[d], 1);
  csrc[pos] = src[e];
  const float4* a = (const float4*)(attr + (size_t)e * 16);
  float4* o = (float4*)(cattr + (size_t)pos * 16);
  o[0] = a[0]; o[1] = a[1]; o[2] = a[2]; o[3] = a[3];
}

// ---------- graph boundaries (batch is sorted) ----------
__global__ void k_gstart(const int* __restrict__ batch, int* __restrict__ gstart,
                         int N, int Gn) {
  int i = blockIdx.x * blockDim.x + threadIdx.x;
  if (i >= N) return;
  int b = batch[i];
  if (i == 0) { for (int g = 0; g <= b; ++g) gstart[g] = 0; }
  else { int bp = batch[i - 1]; for (int g = bp + 1; g <= b; ++g) gstart[g] = i; }
  if (i == N - 1) { for (int g = b + 1; g <= Gn; ++g) gstart[g] = N; }
}

// ---------- fused edge embed + gather + relu + aggregate ----------
// hpa[n] = h[n] + sum_{j in CSR(n)} relu( attr[j]@edge_W + edge_b + h[src[j]] )
__global__ __launch_bounds__(128) void k_edge_agg(const float* __restrict__ h,
    const float* __restrict__ cattr, const int* __restrict__ csrc,
    const int* __restrict__ offs, const float* __restrict__ eW,
    const float* __restrict__ eb, float* __restrict__ hpa) {
  int n = blockIdx.x;
  int c = threadIdx.x;                  // column 0..127
  float w[16];
#pragma unroll
  for (int k = 0; k < 16; ++k) w[k] = eW[k * 128 + c];
  float bias = eb[c];
  int jb = offs[n], je = offs[n + 1];
  jb = __builtin_amdgcn_readfirstlane(jb);
  je = __builtin_amdgcn_readfirstlane(je);
  float acc = 0.f;
  for (int j = jb; j < je; ++j) {
    const float4* ap = (const float4*)(cattr + (size_t)j * 16);
    float4 a0 = ap[0], a1 = ap[1], a2 = ap[2], a3 = ap[3];
    int s = csrc[j];
    float ev = bias;
    ev += a0.x * w[0] + a0.y * w[1] + a0.z * w[2] + a0.w * w[3];
    ev += a1.x * w[4] + a1.y * w[5] + a1.z * w[6] + a1.w * w[7];
    ev += a2.x * w[8] + a2.y * w[9] + a2.z * w[10] + a2.w * w[11];
    ev += a3.x * w[12] + a3.y * w[13] + a3.z * w[14] + a3.w * w[15];
    float hv = h[(size_t)s * 128 + c];
    acc += fmaxf(ev + hv, 0.f);
  }
  size_t o = (size_t)n * 128 + c;
  hpa[o] = h[o] + acc;
}

// ---------- in-place node GEMM: hpa <- hpa @ nn_W + nn_b ----------
// 8 rows per block; rows staged to LDS first so in-place write is safe.
__global__ __launch_bounds__(256) void k_gemm(float* __restrict__ hpa,
    const float* __restrict__ W, const float* __restrict__ b) {
  __shared__ float rows[8][128];
  __shared__ float wbuf[16][128];
  int t = threadIdx.x;
  size_t base = (size_t)blockIdx.x * (8 * 128);
  ((float4*)&rows[0][0])[t] = ((const float4*)(hpa + base))[t];
  int r = t >> 5;
  int cq = (t & 31) * 4;
  float4 acc = make_float4(0.f, 0.f, 0.f, 0.f);
  for (int kc = 0; kc < 8; ++kc) {
    __syncthreads();
    float4* wb4 = (float4*)&wbuf[0][0];
    const float4* gw = (const float4*)(W + (size_t)kc * 16 * 128);
    wb4[t] = gw[t];
    wb4[t + 256] = gw[t + 256];
    __syncthreads();
#pragma unroll
    for (int k = 0; k < 16; ++k) {
      float a = rows[r][kc * 16 + k];
      float4 wv = *(const float4*)&wbuf[k][cq];
      acc.x += a * wv.x; acc.y += a * wv.y;
      acc.z += a * wv.z; acc.w += a * wv.w;
    }
  }
  float4 bv = *(const float4*)(b + cq);
  acc.x += bv.x; acc.y += bv.y; acc.z += bv.z; acc.w += bv.w;
  ((float4*)(hpa + base))[r * 32 + (t & 31)] = acc;
}

// ---------- BN column stats ----------
__global__ __launch_bounds__(256) void k_stats(const float* __restrict__ hc,
    float* __restrict__ colsum, float* __restrict__ colsumsq, int N) {
  int t = threadIdx.x;
  int c = t & 127, half = t >> 7;
  float s = 0.f, s2 = 0.f;
  for (int n = blockIdx.x * 2 + half; n < N; n += gridDim.x * 2) {
    float v = hc[(size_t)n * 128 + c];
    s += v; s2 += v * v;
  }
  __shared__ float ls[256], ls2[256];
  ls[t] = s; ls2[t] = s2; __syncthreads();
  if (t < 128) {
    atomicAdd(&colsum[c], ls[t] + ls[t + 128]);
    atomicAdd(&colsumsq[c], ls2[t] + ls2[t + 128]);
  }
}

// ---------- BN apply + exact GELU + residual: h += gelu(bn(hc)) ----------
__global__ __launch_bounds__(256) void k_bn(const float* __restrict__ hc,
    const float* __restrict__ colsum, const float* __restrict__ colsumsq,
    const float* __restrict__ g, const float* __restrict__ bb,
    float* __restrict__ h, int N) {
  int idx = blockIdx.x * 256 + threadIdx.x;
  if (idx >= N * 32) return;
  int q = idx & 31;
  float invN = 1.f / (float)N;
  float4 cs = ((const float4*)colsum)[q];
  float4 cq = ((const float4*)colsumsq)[q];
  float4 gv = ((const float4*)g)[q];
  float4 bv = ((const float4*)bb)[q];
  float4 v = ((const float4*)hc)[idx];
  float4 hv = ((const float4*)h)[idx];
#define BN1(X)                                                      \
  { float mu = cs.X * invN;                                         \
    float var = cq.X * invN - mu * mu;                              \
    float xn = (v.X - mu) * rsqrtf(var + 1e-5f) * gv.X + bv.X;      \
    hv.X += 0.5f * xn * (1.f + erff(xn * 0.70710678118654752f)); }
  BN1(x) BN1(y) BN1(z) BN1(w)
#undef BN1
  ((float4*)h)[idx] = hv;
}

// ---------- pooled[g] = sum over nodes of graph g of h[n] ----------
__global__ __launch_bounds__(256) void k_pool(const float* __restrict__ h,
    const int* __restrict__ gstart, float* __restrict__ pooled) {
  int g = blockIdx.x;
  int t = threadIdx.x, c = t & 127, half = t >> 7;
  int n0 = gstart[g], n1 = gstart[g + 1];
  float s = 0.f;
  for (int n = n0 + half; n < n1; n += 2) s += h[(size_t)n * 128 + c];
  __shared__ float ls[256];
  ls[t] = s; __syncthreads();
  if (t < 128) pooled[(size_t)g * 128 + c] = ls[t] + ls[t + 128];
}

// ---------- rep[g] = pooled[g] @ lin_W + cnt[g]*lin_b ----------
__global__ __launch_bounds__(256) void k_final(const float* __restrict__ pooled,
    const int* __restrict__ gstart, const float* __restrict__ W,
    const float* __restrict__ b, float* __restrict__ out) {
  int g = blockIdx.x, o = threadIdx.x;
  __shared__ float pr[128];
  if (o < 128) pr[o] = pooled[(size_t)g * 128 + o];
  __syncthreads();
  float cnt = (float)(gstart[g + 1] - gstart[g]);
  float acc = cnt * b[o];
#pragma unroll 8
  for (int k = 0; k < 128; ++k) acc += pr[k] * W[(size_t)k * 256 + o];
  out[(size_t)g * 256 + o] = acc;
}

extern "C" void kernel_launch(void* const* d_in, const int* in_sizes, int n_in,
                              void* d_out, int out_size, void* d_ws, size_t ws_size,
                              hipStream_t stream) {
  const float* x     = (const float*)d_in[0];
  const int*   eidx  = (const int*)d_in[1];
  const float* eattr = (const float*)d_in[2];
  const int*   batch = (const int*)d_in[3];
  const float* embW  = (const float*)d_in[4];
  const float* embB  = (const float*)d_in[5];
  const float* edgeW = (const float*)d_in[6];
  const float* edgeB = (const float*)d_in[7];
  const float* nnW   = (const float*)d_in[8];
  const float* nnB   = (const float*)d_in[9];
  const float* bnG   = (const float*)d_in[10];
  const float* bnB   = (const float*)d_in[11];
  const float* linW  = (const float*)d_in[12];
  const float* linB  = (const float*)d_in[13];
  float* out = (float*)d_out;

  int N = in_sizes[0] / 8;
  int E = in_sizes[1] / 2;
  const int* src = eidx;
  const int* dst = eidx + E;

  // workspace carve-up (~213 MB)
  char* wptr = (char*)d_ws;
  auto alloc = [&](size_t bytes) {
    char* p = wptr; wptr += (bytes + 255) & ~(size_t)255; return p;
  };
  float* h      = (float*)alloc((size_t)N * 128 * 4);
  float* hpa    = (float*)alloc((size_t)N * 128 * 4);   // also hc (in-place GEMM)
  float* cattr  = (float*)alloc((size_t)E * 16 * 4);
  int*   csrc   = (int*)alloc((size_t)E * 4);
  int*   offs   = (int*)alloc((size_t)(N + 1) * 4);
  int*   cursor = (int*)alloc((size_t)N * 4);
  int*   deg    = (int*)alloc((size_t)N * 4);
  int nb = (N + 255) / 256;
  int*   bsum   = (int*)alloc((size_t)nb * 4);
  float* colsum   = (float*)alloc(128 * 4);
  float* colsumsq = (float*)alloc(128 * 4);
  float* pooled   = (float*)alloc((size_t)GG * 128 * 4);
  int*   gstart   = (int*)alloc((size_t)(GG + 1) * 4);

  int q32 = (N * 32 + 255) / 256;

  hipMemsetAsync(deg, 0, (size_t)N * 4, stream);
  k_emb<<<q32, 256, 0, stream>>>(x, embW, embB, h, N);
  k_hist<<<(E + 255) / 256, 256, 0, stream>>>(dst, deg, E);
  k_scan_reduce<<<nb, 256, 0, stream>>>(deg, bsum, N);
  k_scan_mid<<<1, 64, 0, stream>>>(bsum, nb);
  k_scan_final<<<nb, 256, 0, stream>>>(deg, bsum, offs, cursor, N);
  k_fill<<<(E + 255) / 256, 256, 0, stream>>>(src, dst, eattr, cursor, csrc, cattr, E);
  k_gstart<<<(N + 255) / 256, 256, 0, stream>>>(batch, gstart, N, GG);

  for (int l = 0; l < 4; ++l) {
    k_edge_agg<<<N, 128, 0, stream>>>(h, cattr, csrc, offs,
        edgeW + (size_t)l * 16 * 128, edgeB + (size_t)l * 128, hpa);
    k_gemm<<<(N + 7) / 8, 256, 0, stream>>>(hpa,
        nnW + (size_t)l * 128 * 128, nnB + (size_t)l * 128);
    hipMemsetAsync(colsum, 0, 128 * 4, stream);
    hipMemsetAsync(colsumsq, 0, 128 * 4, stream);
    k_stats<<<512, 256, 0, stream>>>(hpa, colsum, colsumsq, N);
    k_bn<<<q32, 256, 0, stream>>>(hpa, colsum, colsumsq,
        bnG + (size_t)l * 128, bnB + (size_t)l * 128, h, N);
  }
  k_pool<<<GG, 256, 0, stream>>>(h, gstart, pooled);
  k_final<<<GG, 256, 0, stream>>>(pooled, gstart, linW, linB, out);
}

// Round 2
// 1674.049 us; speedup vs baseline: 1.1502x; 1.1502x over previous
//
#include <hip/hip_runtime.h>
#include <math.h>

// Problem constants (from reference): N=100000, E=1600000, F_IN=8, H=128,
// L=4, E_FEAT=16, G=256, OUT=256. N/E derived from in_sizes at launch.
#define GG 256

// ---------- h = x @ emb_W + emb_b  ([N,8]@[8,128]) ----------
__global__ __launch_bounds__(256) void k_emb(const float* __restrict__ x,
    const float* __restrict__ W, const float* __restrict__ b,
    float* __restrict__ h, int N) {
  int idx = blockIdx.x * 256 + threadIdx.x;      // one float4 of output per thread
  if (idx >= N * 32) return;
  int n = idx >> 5, q = idx & 31;
  const float* xr = x + (size_t)n * 8;
  float xs[8];
#pragma unroll
  for (int k = 0; k < 8; ++k) xs[k] = xr[k];
  float4 acc = ((const float4*)b)[q];
#pragma unroll
  for (int k = 0; k < 8; ++k) {
    float4 w = ((const float4*)(W + (size_t)k * 128))[q];
    acc.x += xs[k] * w.x; acc.y += xs[k] * w.y;
    acc.z += xs[k] * w.z; acc.w += xs[k] * w.w;
  }
  ((float4*)h)[idx] = acc;
}

// ---------- CSR build ----------
__global__ void k_hist(const int* __restrict__ dst, int* __restrict__ deg, int E) {
  int e = blockIdx.x * blockDim.x + threadIdx.x;
  if (e < E) atomicAdd(&deg[dst[e]], 1);
}

__global__ __launch_bounds__(256) void k_scan_reduce(const int* __restrict__ deg,
    int* __restrict__ bsum, int N) {
  __shared__ int sd[256];
  int i = blockIdx.x * 256 + threadIdx.x;
  sd[threadIdx.x] = (i < N) ? deg[i] : 0;
  __syncthreads();
  for (int s = 128; s > 0; s >>= 1) {
    if (threadIdx.x < s) sd[threadIdx.x] += sd[threadIdx.x + s];
    __syncthreads();
  }
  if (threadIdx.x == 0) bsum[blockIdx.x] = sd[0];
}

// single-block exclusive scan over nb (<=512) block sums
__global__ __launch_bounds__(512) void k_scan_mid(int* bsum, int nb) {
  __shared__ int sd[512];
  int t = threadIdx.x;
  int v = (t < nb) ? bsum[t] : 0;
  sd[t] = v; __syncthreads();
  for (int d = 1; d < 512; d <<= 1) {
    int xv = (t >= d) ? sd[t - d] : 0;
    __syncthreads();
    sd[t] += xv;
    __syncthreads();
  }
  if (t < nb) bsum[t] = sd[t] - v;   // exclusive
}

__global__ __launch_bounds__(256) void k_scan_final(const int* __restrict__ deg,
    const int* __restrict__ bsum, int* __restrict__ offs,
    int* __restrict__ cursor, int N) {
  __shared__ int sd[256];
  int t = threadIdx.x;
  int i = blockIdx.x * 256 + t;
  int v = (i < N) ? deg[i] : 0;
  sd[t] = v; __syncthreads();
  for (int d = 1; d < 256; d <<= 1) {           // Hillis-Steele inclusive scan
    int xv = (t >= d) ? sd[t - d] : 0;
    __syncthreads();
    sd[t] += xv;
    __syncthreads();
  }
  int off = bsum[blockIdx.x] + sd[t] - v;       // exclusive
  if (i < N) {
    offs[i] = off; cursor[i] = off;
    if (i == N - 1) offs[N] = off + v;
  }
}

__global__ void k_fill(const int* __restrict__ src, const int* __restrict__ dst,
    const float* __restrict__ attr, int* __restrict__ cursor,
    int* __restrict__ csrc, float* __restrict__ cattr, int E) {
  int e = blockIdx.x * blockDim.x + threadIdx.x;
  if (e >= E) return;
  int d = dst[e];
  int pos = atomicAdd(&cursor[d], 1);
  csrc[pos] = src[e];
  const float4* a = (const float4*)(attr + (size_t)e * 16);
  float4* o = (float4*)(cattr + (size_t)pos * 16);
  o[0] = a[0]; o[1] = a[1]; o[2] = a[2]; o[3] = a[3];
}

// ---------- graph boundaries (batch is sorted) ----------
__global__ void k_gstart(const int* __restrict__ batch, int* __restrict__ gstart,
                         int N, int Gn) {
  int i = blockIdx.x * blockDim.x + threadIdx.x;
  if (i >= N) return;
  int b = batch[i];
  if (i == 0) { for (int g = 0; g <= b; ++g) gstart[g] = 0; }
  else { int bp = batch[i - 1]; for (int g = bp + 1; g <= b; ++g) gstart[g] = i; }
  if (i == N - 1) { for (int g = b + 1; g <= Gn; ++g) gstart[g] = N; }
}

// ---------- fused edge embed + gather + relu + aggregate ----------
// hpa[n] = h[n] + sum_{j in CSR(n)} relu( attr[j]@edge_W + edge_b + h[src[j]] )
// Unrolled x4 with independent accumulators: 4 gathers in flight per wave.
__global__ __launch_bounds__(128) void k_edge_agg(const float* __restrict__ h,
    const float* __restrict__ cattr, const int* __restrict__ csrc,
    const int* __restrict__ offs, const float* __restrict__ eW,
    const float* __restrict__ eb, float* __restrict__ hpa) {
  int n = blockIdx.x;
  int c = threadIdx.x;                  // column 0..127
  float w[16];
#pragma unroll
  for (int k = 0; k < 16; ++k) w[k] = eW[k * 128 + c];
  float bias = eb[c];
  const float* hc_base = h + c;
  int jb = offs[n], je = offs[n + 1];
  jb = __builtin_amdgcn_readfirstlane(jb);
  je = __builtin_amdgcn_readfirstlane(je);

#define EDGE(JJ, ACC)                                                       \
  {                                                                         \
    int s = csrc[(JJ)];                                                     \
    const float4* ap = (const float4*)(cattr + (size_t)(JJ) * 16);          \
    float4 a0 = ap[0], a1 = ap[1], a2 = ap[2], a3 = ap[3];                  \
    float hv = hc_base[(size_t)s * 128];                                    \
    float ev = bias;                                                        \
    ev += a0.x * w[0] + a0.y * w[1] + a0.z * w[2] + a0.w * w[3];            \
    ev += a1.x * w[4] + a1.y * w[5] + a1.z * w[6] + a1.w * w[7];            \
    ev += a2.x * w[8] + a2.y * w[9] + a2.z * w[10] + a2.w * w[11];          \
    ev += a3.x * w[12] + a3.y * w[13] + a3.z * w[14] + a3.w * w[15];        \
    ACC += fmaxf(ev + hv, 0.f);                                             \
  }

  float acc0 = 0.f, acc1 = 0.f, acc2 = 0.f, acc3 = 0.f;
  int j = jb;
  for (; j + 4 <= je; j += 4) {
    EDGE(j, acc0)
    EDGE(j + 1, acc1)
    EDGE(j + 2, acc2)
    EDGE(j + 3, acc3)
  }
  for (; j < je; ++j) EDGE(j, acc0)
#undef EDGE
  size_t o = (size_t)n * 128 + c;
  hpa[o] = h[o] + ((acc0 + acc1) + (acc2 + acc3));
}

// ---------- in-place node GEMM: hpa <- hpa @ nn_W + nn_b ----------
// 8 rows per block; rows staged to LDS first so in-place write is safe.
// Block 0 additionally zeroes the BN stats buffer (runs before k_stats).
__global__ __launch_bounds__(256) void k_gemm(float* __restrict__ hpa,
    const float* __restrict__ W, const float* __restrict__ b,
    float* __restrict__ cstats) {
  __shared__ float rows[8][128];
  __shared__ float wbuf[16][128];
  int t = threadIdx.x;
  if (blockIdx.x == 0) cstats[t] = 0.f;   // zero colsum[128]+colsumsq[128]
  size_t base = (size_t)blockIdx.x * (8 * 128);
  ((float4*)&rows[0][0])[t] = ((const float4*)(hpa + base))[t];
  int r = t >> 5;
  int cq = (t & 31) * 4;
  float4 acc = make_float4(0.f, 0.f, 0.f, 0.f);
  for (int kc = 0; kc < 8; ++kc) {
    __syncthreads();
    float4* wb4 = (float4*)&wbuf[0][0];
    const float4* gw = (const float4*)(W + (size_t)kc * 16 * 128);
    wb4[t] = gw[t];
    wb4[t + 256] = gw[t + 256];
    __syncthreads();
#pragma unroll
    for (int k = 0; k < 16; ++k) {
      float a = rows[r][kc * 16 + k];
      float4 wv = *(const float4*)&wbuf[k][cq];
      acc.x += a * wv.x; acc.y += a * wv.y;
      acc.z += a * wv.z; acc.w += a * wv.w;
    }
  }
  float4 bv = *(const float4*)(b + cq);
  acc.x += bv.x; acc.y += bv.y; acc.z += bv.z; acc.w += bv.w;
  ((float4*)(hpa + base))[r * 32 + (t & 31)] = acc;
}

// ---------- BN column stats (into cstats[0:128]=sum, [128:256]=sumsq) ----------
__global__ __launch_bounds__(256) void k_stats(const float* __restrict__ hc,
    float* __restrict__ cstats, int N) {
  int t = threadIdx.x;
  int c = t & 127, half = t >> 7;
  float s = 0.f, s2 = 0.f;
  for (int n = blockIdx.x * 2 + half; n < N; n += gridDim.x * 2) {
    float v = hc[(size_t)n * 128 + c];
    s += v; s2 += v * v;
  }
  __shared__ float ls[256], ls2[256];
  ls[t] = s; ls2[t] = s2; __syncthreads();
  if (t < 128) {
    atomicAdd(&cstats[c], ls[t] + ls[t + 128]);
    atomicAdd(&cstats[128 + c], ls2[t] + ls2[t + 128]);
  }
}

// ---------- BN apply + exact GELU + residual: h += gelu(bn(hc)) ----------
__global__ __launch_bounds__(256) void k_bn(const float* __restrict__ hc,
    const float* __restrict__ cstats,
    const float* __restrict__ g, const float* __restrict__ bb,
    float* __restrict__ h, int N) {
  int idx = blockIdx.x * 256 + threadIdx.x;
  if (idx >= N * 32) return;
  int q = idx & 31;
  float invN = 1.f / (float)N;
  float4 cs = ((const float4*)cstats)[q];
  float4 cq = ((const float4*)cstats)[q + 32];
  float4 gv = ((const float4*)g)[q];
  float4 bv = ((const float4*)bb)[q];
  float4 v = ((const float4*)hc)[idx];
  float4 hv = ((const float4*)h)[idx];
#define BN1(X)                                                      \
  { float mu = cs.X * invN;                                         \
    float var = cq.X * invN - mu * mu;                              \
    float xn = (v.X - mu) * rsqrtf(var + 1e-5f) * gv.X + bv.X;      \
    hv.X += 0.5f * xn * (1.f + erff(xn * 0.70710678118654752f)); }
  BN1(x) BN1(y) BN1(z) BN1(w)
#undef BN1
  ((float4*)h)[idx] = hv;
}

// ---------- pooled[g] = sum over nodes of graph g of h[n] ----------
__global__ __launch_bounds__(256) void k_pool(const float* __restrict__ h,
    const int* __restrict__ gstart, float* __restrict__ pooled) {
  int g = blockIdx.x;
  int t = threadIdx.x, c = t & 127, half = t >> 7;
  int n0 = gstart[g], n1 = gstart[g + 1];
  float s = 0.f;
  for (int n = n0 + half; n < n1; n += 2) s += h[(size_t)n * 128 + c];
  __shared__ float ls[256];
  ls[t] = s; __syncthreads();
  if (t < 128) pooled[(size_t)g * 128 + c] = ls[t] + ls[t + 128];
}

// ---------- rep[g] = pooled[g] @ lin_W + cnt[g]*lin_b ----------
__global__ __launch_bounds__(256) void k_final(const float* __restrict__ pooled,
    const int* __restrict__ gstart, const float* __restrict__ W,
    const float* __restrict__ b, float* __restrict__ out) {
  int g = blockIdx.x, o = threadIdx.x;
  __shared__ float pr[128];
  if (o < 128) pr[o] = pooled[(size_t)g * 128 + o];
  __syncthreads();
  float cnt = (float)(gstart[g + 1] - gstart[g]);
  float acc = cnt * b[o];
#pragma unroll 8
  for (int k = 0; k < 128; ++k) acc += pr[k] * W[(size_t)k * 256 + o];
  out[(size_t)g * 256 + o] = acc;
}

extern "C" void kernel_launch(void* const* d_in, const int* in_sizes, int n_in,
                              void* d_out, int out_size, void* d_ws, size_t ws_size,
                              hipStream_t stream) {
  const float* x     = (const float*)d_in[0];
  const int*   eidx  = (const int*)d_in[1];
  const float* eattr = (const float*)d_in[2];
  const int*   batch = (const int*)d_in[3];
  const float* embW  = (const float*)d_in[4];
  const float* embB  = (const float*)d_in[5];
  const float* edgeW = (const float*)d_in[6];
  const float* edgeB = (const float*)d_in[7];
  const float* nnW   = (const float*)d_in[8];
  const float* nnB   = (const float*)d_in[9];
  const float* bnG   = (const float*)d_in[10];
  const float* bnB   = (const float*)d_in[11];
  const float* linW  = (const float*)d_in[12];
  const float* linB  = (const float*)d_in[13];
  float* out = (float*)d_out;

  int N = in_sizes[0] / 8;
  int E = in_sizes[1] / 2;
  const int* src = eidx;
  const int* dst = eidx + E;

  // workspace carve-up (~213 MB)
  char* wptr = (char*)d_ws;
  auto alloc = [&](size_t bytes) {
    char* p = wptr; wptr += (bytes + 255) & ~(size_t)255; return p;
  };
  float* h      = (float*)alloc((size_t)N * 128 * 4);
  float* hpa    = (float*)alloc((size_t)N * 128 * 4);   // also hc (in-place GEMM)
  float* cattr  = (float*)alloc((size_t)E * 16 * 4);
  int*   csrc   = (int*)alloc((size_t)E * 4);
  int*   offs   = (int*)alloc((size_t)(N + 1) * 4);
  int*   cursor = (int*)alloc((size_t)N * 4);
  int*   deg    = (int*)alloc((size_t)N * 4);
  int nb = (N + 255) / 256;
  int*   bsum   = (int*)alloc((size_t)nb * 4);
  float* cstats = (float*)alloc(256 * 4);               // colsum | colsumsq
  float* pooled = (float*)alloc((size_t)GG * 128 * 4);
  int*   gstart = (int*)alloc((size_t)(GG + 1) * 4);

  int q32 = (N * 32 + 255) / 256;

  hipMemsetAsync(deg, 0, (size_t)N * 4, stream);
  k_emb<<<q32, 256, 0, stream>>>(x, embW, embB, h, N);
  k_hist<<<(E + 255) / 256, 256, 0, stream>>>(dst, deg, E);
  k_scan_reduce<<<nb, 256, 0, stream>>>(deg, bsum, N);
  k_scan_mid<<<1, 512, 0, stream>>>(bsum, nb);
  k_scan_final<<<nb, 256, 0, stream>>>(deg, bsum, offs, cursor, N);
  k_fill<<<(E + 255) / 256, 256, 0, stream>>>(src, dst, eattr, cursor, csrc, cattr, E);
  k_gstart<<<(N + 255) / 256, 256, 0, stream>>>(batch, gstart, N, GG);

  for (int l = 0; l < 4; ++l) {
    k_edge_agg<<<N, 128, 0, stream>>>(h, cattr, csrc, offs,
        edgeW + (size_t)l * 16 * 128, edgeB + (size_t)l * 128, hpa);
    k_gemm<<<(N + 7) / 8, 256, 0, stream>>>(hpa,
        nnW + (size_t)l * 128 * 128, nnB + (size_t)l * 128, cstats);
    k_stats<<<512, 256, 0, stream>>>(hpa, cstats, N);
    k_bn<<<q32, 256, 0, stream>>>(hpa, cstats,
        bnG + (size_t)l * 128, bnB + (size_t)l * 128, h, N);
  }
  k_pool<<<GG, 256, 0, stream>>>(h, gstart, pooled);
  k_final<<<GG, 256, 0, stream>>>(pooled, gstart, linW, linB, out);
}